// Round 2
// baseline (34440.814 us; speedup 1.0000x reference)
//
#include <hip/hip_runtime.h>
#include <hip/hip_bf16.h>

// Problem constants
#define BATCH 1024
#define SEQ   350
#define LAT   512
#define VOC   41
#define H0D   512
#define H1D   256
#define H2D   128
#define H3D   32
#define G1    768   // 3*H1D
#define G2    384   // 3*H2D
#define G3    96    // 3*H3D
#define SOS   1

// ws layout (floats)
#define O_HH0   0         // wt_hh0 [256][768]
#define O_IH1   196608    // wt_ih1 [256][384]
#define O_HH1   294912    // wt_hh1 [128][384]
#define O_IH2   344064    // wt_ih2 [128][96]
#define O_HH2   356352    // wt_hh2 [32][96]
#define O_PROJ  359424    // wt_proj [32][41]
#define O_TAB   360736    // gi0 table [41][768]
#define WS_FLOATS 392224

#define RT 4  // batch rows per block

__global__ void setup_kernel(const float* __restrict__ Whh0, const float* __restrict__ Wih1,
                             const float* __restrict__ Whh1, const float* __restrict__ Wih2,
                             const float* __restrict__ Whh2, const float* __restrict__ Wproj,
                             const float* __restrict__ Wemb, const float* __restrict__ bemb,
                             const float* __restrict__ Wih0, const float* __restrict__ bih0,
                             float* __restrict__ ws) {
  int idx = blockIdx.x * blockDim.x + threadIdx.x;
  if (idx < 196608) { int o = idx % G1, k = idx / G1; ws[O_HH0 + k*G1 + o] = Whh0[o*H1D + k]; return; }
  idx -= 196608;
  if (idx < 98304)  { int o = idx % G2, k = idx / G2; ws[O_IH1 + k*G2 + o] = Wih1[o*H1D + k]; return; }
  idx -= 98304;
  if (idx < 49152)  { int o = idx % G2, k = idx / G2; ws[O_HH1 + k*G2 + o] = Whh1[o*H2D + k]; return; }
  idx -= 49152;
  if (idx < 12288)  { int o = idx % G3, k = idx / G3; ws[O_IH2 + k*G3 + o] = Wih2[o*H2D + k]; return; }
  idx -= 12288;
  if (idx < 3072)   { int o = idx % G3, k = idx / G3; ws[O_HH2 + k*G3 + o] = Whh2[o*H3D + k]; return; }
  idx -= 3072;
  if (idx < 1312)   { int o = idx % VOC, k = idx / VOC; ws[O_PROJ + k*VOC + o] = Wproj[o*H3D + k]; return; }
  idx -= 1312;
  if (idx < 31488) {
    // gi0 table: exact (f64-accumulated) x@Wih0.T + bih0 per token value.
    int o = idx % G1, v = idx / G1;
    double acc = (double)bih0[o];
    const float* wrow = Wih0 + (size_t)o * H0D;
    for (int k = 0; k < H0D; ++k)
      acc += ((double)Wemb[k*VOC + v] + (double)bemb[k]) * (double)wrow[k];
    ws[O_TAB + v*G1 + o] = (float)acc;
  }
}

__device__ __forceinline__ double sigmd(double x) { return 1.0 / (1.0 + exp(-x)); }

__global__ __launch_bounds__(256) void gru_persist(
    const float* __restrict__ latent, const int* __restrict__ tgt,
    const float* __restrict__ Winit, const float* __restrict__ binit,
    const float* __restrict__ bhh0,
    const float* __restrict__ bih1, const float* __restrict__ bhh1,
    const float* __restrict__ bih2, const float* __restrict__ bhh2,
    const float* __restrict__ bproj,
    const float* __restrict__ ws, float* __restrict__ out)
{
  const int tid = threadIdx.x;
  const int r0 = blockIdx.x * RT;

  const float* wt_hh0 = ws + O_HH0;
  const float* wt_ih1 = ws + O_IH1;
  const float* wt_hh1 = ws + O_HH1;
  const float* wt_ih2 = ws + O_IH2;
  const float* wt_hh2 = ws + O_HH2;
  const float* wt_proj = ws + O_PROJ;
  const float* tab = ws + O_TAB;

  float* __restrict__ out_logits = out;
  float* __restrict__ out_pred = out + (size_t)BATCH * SEQ * VOC;

  __shared__ float h0s[RT][H1D];
  __shared__ float h1s[RT][H2D];
  __shared__ float h2s[RT][H3D];
  __shared__ float sc_gh1[RT][G2];
  __shared__ float sc_c[5][3][RT][H3D];
  __shared__ float sc_log[RT][VOC];
  __shared__ int toks[RT];

  // ---- init hidden states: combined = latent @ Winit.T + binit (f64 accumulate)
  for (int idx = tid; idx < RT * 416; idx += 256) {
    int r = idx / 416, jj = idx - r * 416;
    const float* lrow = latent + (size_t)(r0 + r) * LAT;
    const float* wrow = Winit + (size_t)jj * LAT;
    double acc = (double)binit[jj];
    for (int k = 0; k < LAT; ++k) acc += (double)lrow[k] * (double)wrow[k];
    float a = (float)acc;
    if (jj < H1D) h0s[r][jj] = a;
    else if (jj < H1D + H2D) h1s[r][jj - H1D] = a;
    else h2s[r][jj - H1D - H2D] = a;
  }
  __syncthreads();

  for (int t = 0; t < SEQ; ++t) {
    if (tid < RT) toks[tid] = (t == 0) ? SOS : tgt[(size_t)(r0 + tid) * SEQ + t];

    // ======== Stage A: GRU0 (cols = tid, K=256 over h0s) ========
    const int j = tid;
    double aR[RT], aZ[RT], aN[RT];
    #pragma unroll
    for (int r = 0; r < RT; ++r) { aR[r] = 0.0; aZ[r] = 0.0; aN[r] = 0.0; }
    {
      const float* __restrict__ wbase = wt_hh0 + j;
      for (int kb = 0; kb < H1D; kb += 4) {
        float4 hv[RT];
        #pragma unroll
        for (int r = 0; r < RT; ++r) hv[r] = *(const float4*)&h0s[r][kb];
        #pragma unroll
        for (int u = 0; u < 4; ++u) {
          const float* wp = wbase + (size_t)(kb + u) * G1;
          double wr = (double)wp[0], wz = (double)wp[256], wn = (double)wp[512];
          #pragma unroll
          for (int r = 0; r < RT; ++r) {
            double hval = (double)((const float*)&hv[r])[u];
            aR[r] = fma(hval, wr, aR[r]);
            aZ[r] = fma(hval, wz, aZ[r]);
            aN[r] = fma(hval, wn, aN[r]);
          }
        }
      }
    }
    __syncthreads();  // B1: h0s reads done; toks visible
    {
      const double bR = (double)bhh0[j], bZ = (double)bhh0[256 + j], bN = (double)bhh0[512 + j];
      float h0n[RT];
      #pragma unroll
      for (int r = 0; r < RT; ++r) {
        const float* trow = tab + (size_t)toks[r] * G1;
        double gR = (double)trow[j] + aR[r] + bR;
        double gZ = (double)trow[256 + j] + aZ[r] + bZ;
        double giN = (double)trow[512 + j];
        double ghN = aN[r] + bN;
        double rg = sigmd(gR);
        double zg = sigmd(gZ);
        double ng = tanh(fma(rg, ghN, giN));
        h0n[r] = (float)((1.0 - zg) * ng + zg * (double)h0s[r][j]);
      }
      #pragma unroll
      for (int r = 0; r < RT; ++r) h0s[r][j] = h0n[r];
    }
    __syncthreads();  // B2: h0s new visible

    // ======== Stage B: GRU1 (cols = tid&127; half0: gi1 K=256, half1: gh1 K=128) ========
    const int jb = tid & 127;
    const int hb = tid >> 7;
    double bRv[RT], bZv[RT], bNv[RT];
    #pragma unroll
    for (int r = 0; r < RT; ++r) { bRv[r] = 0.0; bZv[r] = 0.0; bNv[r] = 0.0; }
    if (hb == 0) {
      const float* __restrict__ wbase = wt_ih1 + jb;
      for (int kb = 0; kb < H1D; kb += 4) {
        float4 hv[RT];
        #pragma unroll
        for (int r = 0; r < RT; ++r) hv[r] = *(const float4*)&h0s[r][kb];
        #pragma unroll
        for (int u = 0; u < 4; ++u) {
          const float* wp = wbase + (size_t)(kb + u) * G2;
          double wr = (double)wp[0], wz = (double)wp[128], wn = (double)wp[256];
          #pragma unroll
          for (int r = 0; r < RT; ++r) {
            double hval = (double)((const float*)&hv[r])[u];
            bRv[r] = fma(hval, wr, bRv[r]);
            bZv[r] = fma(hval, wz, bZv[r]);
            bNv[r] = fma(hval, wn, bNv[r]);
          }
        }
      }
    } else {
      const float* __restrict__ wbase = wt_hh1 + jb;
      for (int kb = 0; kb < H2D; kb += 4) {
        float4 hv[RT];
        #pragma unroll
        for (int r = 0; r < RT; ++r) hv[r] = *(const float4*)&h1s[r][kb];
        #pragma unroll
        for (int u = 0; u < 4; ++u) {
          const float* wp = wbase + (size_t)(kb + u) * G2;
          double wr = (double)wp[0], wz = (double)wp[128], wn = (double)wp[256];
          #pragma unroll
          for (int r = 0; r < RT; ++r) {
            double hval = (double)((const float*)&hv[r])[u];
            bRv[r] = fma(hval, wr, bRv[r]);
            bZv[r] = fma(hval, wz, bZv[r]);
            bNv[r] = fma(hval, wn, bNv[r]);
          }
        }
      }
      const double bR = (double)bhh1[jb], bZ = (double)bhh1[128 + jb], bN = (double)bhh1[256 + jb];
      #pragma unroll
      for (int r = 0; r < RT; ++r) {
        sc_gh1[r][jb] = (float)(bRv[r] + bR);
        sc_gh1[r][128 + jb] = (float)(bZv[r] + bZ);
        sc_gh1[r][256 + jb] = (float)(bNv[r] + bN);
      }
    }
    __syncthreads();  // B3: gh1 partials visible; h1s reads done
    if (hb == 0) {
      const double bR = (double)bih1[jb], bZ = (double)bih1[128 + jb], bN = (double)bih1[256 + jb];
      float h1n[RT];
      #pragma unroll
      for (int r = 0; r < RT; ++r) {
        double gR = bRv[r] + bR + (double)sc_gh1[r][jb];
        double gZ = bZv[r] + bZ + (double)sc_gh1[r][128 + jb];
        double giN = bNv[r] + bN;
        double ghN = (double)sc_gh1[r][256 + jb];
        double rg = sigmd(gR);
        double zg = sigmd(gZ);
        double ng = tanh(fma(rg, ghN, giN));
        h1n[r] = (float)((1.0 - zg) * ng + zg * (double)h1s[r][jb]);
      }
      #pragma unroll
      for (int r = 0; r < RT; ++r) h1s[r][jb] = h1n[r];
    }
    __syncthreads();  // B4: h1s new visible

    // ======== Stage C: GRU2 (cols = tid&31; groups split K) ========
    const int jc = tid & 31;
    const int scg = tid >> 5;  // 0..7
    double cR[RT], cZ[RT], cN[RT];
    #pragma unroll
    for (int r = 0; r < RT; ++r) { cR[r] = 0.0; cZ[r] = 0.0; cN[r] = 0.0; }
    if (scg < 4) {  // gi2 over h1s, k-slice [scg*32, +32)
      for (int kk = 0; kk < 32; ++kk) {
        int k = scg * 32 + kk;
        const float* wp = wt_ih2 + (size_t)k * G3;
        double wr = (double)wp[jc], wz = (double)wp[32 + jc], wn = (double)wp[64 + jc];
        #pragma unroll
        for (int r = 0; r < RT; ++r) {
          double hval = (double)h1s[r][k];
          cR[r] = fma(hval, wr, cR[r]);
          cZ[r] = fma(hval, wz, cZ[r]);
          cN[r] = fma(hval, wn, cN[r]);
        }
      }
    } else if (scg == 4) {  // gh2 over h2s, K=32
      for (int k = 0; k < 32; ++k) {
        const float* wp = wt_hh2 + (size_t)k * G3;
        double wr = (double)wp[jc], wz = (double)wp[32 + jc], wn = (double)wp[64 + jc];
        #pragma unroll
        for (int r = 0; r < RT; ++r) {
          double hval = (double)h2s[r][k];
          cR[r] = fma(hval, wr, cR[r]);
          cZ[r] = fma(hval, wz, cZ[r]);
          cN[r] = fma(hval, wn, cN[r]);
        }
      }
    }
    if (scg < 5) {
      // store partials as f32 pairs (hi+lo) to keep f64 accuracy through LDS:
      // value magnitudes here are O(1); single f32 rounding of a partial is ~6e-8,
      // well below the argmax gap floor — plain f32 is sufficient.
      #pragma unroll
      for (int r = 0; r < RT; ++r) {
        sc_c[scg][0][r][jc] = (float)cR[r];
        sc_c[scg][1][r][jc] = (float)cZ[r];
        sc_c[scg][2][r][jc] = (float)cN[r];
      }
    }
    __syncthreads();  // B5: partials visible
    if (tid < 128) {
      int r = tid >> 5, jj = tid & 31;
      double giR = (double)sc_c[0][0][r][jj] + (double)sc_c[1][0][r][jj] + (double)sc_c[2][0][r][jj] + (double)sc_c[3][0][r][jj] + (double)bih2[jj];
      double giZ = (double)sc_c[0][1][r][jj] + (double)sc_c[1][1][r][jj] + (double)sc_c[2][1][r][jj] + (double)sc_c[3][1][r][jj] + (double)bih2[32 + jj];
      double giN = (double)sc_c[0][2][r][jj] + (double)sc_c[1][2][r][jj] + (double)sc_c[2][2][r][jj] + (double)sc_c[3][2][r][jj] + (double)bih2[64 + jj];
      double ghR = (double)sc_c[4][0][r][jj] + (double)bhh2[jj];
      double ghZ = (double)sc_c[4][1][r][jj] + (double)bhh2[32 + jj];
      double ghN = (double)sc_c[4][2][r][jj] + (double)bhh2[64 + jj];
      double rg = sigmd(giR + ghR);
      double zg = sigmd(giZ + ghZ);
      double ng = tanh(fma(rg, ghN, giN));
      h2s[r][jj] = (float)((1.0 - zg) * ng + zg * (double)h2s[r][jj]);
    }
    __syncthreads();  // B6: h2s new visible

    // ======== Stage D: projection + argmax ========
    if (tid < RT * VOC) {
      int r = tid / VOC, c = tid - r * VOC;
      double acc = (double)bproj[c];
      #pragma unroll
      for (int k = 0; k < H3D; ++k)
        acc = fma((double)h2s[r][k], (double)wt_proj[k * VOC + c], acc);
      float accf = (float)acc;
      out_logits[((size_t)(r0 + r) * SEQ + t) * VOC + c] = accf;
      sc_log[r][c] = accf;
    }
    __syncthreads();  // B7: logits visible
    if (tid < RT) {
      float best = sc_log[tid][0];
      int bi = 0;
      #pragma unroll
      for (int c = 1; c < VOC; ++c) {
        float v = sc_log[tid][c];
        if (v > best) { best = v; bi = c; }
      }
      out_pred[(size_t)(r0 + tid) * SEQ + t] = (float)bi;
    }
    // no trailing barrier needed: toks/sc_log writers are the same tid<RT threads,
    // and all cross-thread reuse is separated by B1..B7 of the next iteration.
  }
}

extern "C" void kernel_launch(void* const* d_in, const int* in_sizes, int n_in,
                              void* d_out, int out_size, void* d_ws, size_t ws_size,
                              hipStream_t stream) {
  const float* latent  = (const float*)d_in[0];
  const int*   tgt     = (const int*)d_in[1];
  const float* Wemb    = (const float*)d_in[2];
  const float* bemb    = (const float*)d_in[3];
  const float* Winit   = (const float*)d_in[4];
  const float* binit   = (const float*)d_in[5];
  const float* Wih0    = (const float*)d_in[6];
  const float* Whh0    = (const float*)d_in[7];
  const float* bih0    = (const float*)d_in[8];
  const float* bhh0    = (const float*)d_in[9];
  const float* Wih1    = (const float*)d_in[10];
  const float* Whh1    = (const float*)d_in[11];
  const float* bih1    = (const float*)d_in[12];
  const float* bhh1    = (const float*)d_in[13];
  const float* Wih2    = (const float*)d_in[14];
  const float* Whh2    = (const float*)d_in[15];
  const float* bih2    = (const float*)d_in[16];
  const float* bhh2    = (const float*)d_in[17];
  const float* Wproj   = (const float*)d_in[18];
  const float* bproj   = (const float*)d_in[19];

  float* ws = (float*)d_ws;
  float* out = (float*)d_out;

  int setup_threads = WS_FLOATS;
  int setup_blocks = (setup_threads + 255) / 256;
  setup_kernel<<<setup_blocks, 256, 0, stream>>>(Whh0, Wih1, Whh1, Wih2, Whh2, Wproj,
                                                Wemb, bemb, Wih0, bih0, ws);

  gru_persist<<<BATCH / RT, 256, 0, stream>>>(latent, tgt, Winit, binit,
                                              bhh0, bih1, bhh1, bih2, bhh2, bproj,
                                              ws, out);
}

// Round 3
// 11710.635 us; speedup vs baseline: 2.9410x; 2.9410x over previous
//
#include <hip/hip_runtime.h>
#include <hip/hip_bf16.h>

// Problem constants
#define BATCH 1024
#define SEQ   350
#define LAT   512
#define VOC   41
#define H0D   512
#define H1D   256
#define H2D   128
#define H3D   32
#define G1    768   // 3*H1D
#define G2    384   // 3*H2D
#define G3    96    // 3*H3D
#define SOS   1

// ws layout (floats)
#define O_HH0   0         // wt_hh0 [256][768]
#define O_IH1   196608    // wt_ih1 [256][384]
#define O_HH1   294912    // wt_hh1 [128][384]
#define O_IH2   344064    // wt_ih2 [128][96]
#define O_HH2   356352    // wt_hh2 [32][96]
#define O_PROJ  359424    // wt_proj [32][41]
#define O_TAB   360736    // gi0 table [41][768]
#define WS_FLOATS 392224

#define RT 4    // batch rows per block
#define NT 512  // threads per block (8 waves)

__global__ void setup_kernel(const float* __restrict__ Whh0, const float* __restrict__ Wih1,
                             const float* __restrict__ Whh1, const float* __restrict__ Wih2,
                             const float* __restrict__ Whh2, const float* __restrict__ Wproj,
                             const float* __restrict__ Wemb, const float* __restrict__ bemb,
                             const float* __restrict__ Wih0, const float* __restrict__ bih0,
                             float* __restrict__ ws) {
  int idx = blockIdx.x * blockDim.x + threadIdx.x;
  if (idx < 196608) { int o = idx % G1, k = idx / G1; ws[O_HH0 + k*G1 + o] = Whh0[o*H1D + k]; return; }
  idx -= 196608;
  if (idx < 98304)  { int o = idx % G2, k = idx / G2; ws[O_IH1 + k*G2 + o] = Wih1[o*H1D + k]; return; }
  idx -= 98304;
  if (idx < 49152)  { int o = idx % G2, k = idx / G2; ws[O_HH1 + k*G2 + o] = Whh1[o*H2D + k]; return; }
  idx -= 49152;
  if (idx < 12288)  { int o = idx % G3, k = idx / G3; ws[O_IH2 + k*G3 + o] = Wih2[o*H2D + k]; return; }
  idx -= 12288;
  if (idx < 3072)   { int o = idx % G3, k = idx / G3; ws[O_HH2 + k*G3 + o] = Whh2[o*H3D + k]; return; }
  idx -= 3072;
  if (idx < 1312)   { int o = idx % VOC, k = idx / VOC; ws[O_PROJ + k*VOC + o] = Wproj[o*H3D + k]; return; }
  idx -= 1312;
  if (idx < 31488) {
    // gi0 table: exact (f64-accumulated) x@Wih0.T + bih0 per token value.
    int o = idx % G1, v = idx / G1;
    double acc = (double)bih0[o];
    const float* wrow = Wih0 + (size_t)o * H0D;
    for (int k = 0; k < H0D; ++k)
      acc += ((double)Wemb[k*VOC + v] + (double)bemb[k]) * (double)wrow[k];
    ws[O_TAB + v*G1 + o] = (float)acc;
  }
}

__device__ __forceinline__ double sigmd(double x) { return 1.0 / (1.0 + exp(-x)); }

__global__ __launch_bounds__(NT, 2) void gru_persist(
    const float* __restrict__ latent, const int* __restrict__ tgt,
    const float* __restrict__ Winit, const float* __restrict__ binit,
    const float* __restrict__ bhh0,
    const float* __restrict__ bih1, const float* __restrict__ bhh1,
    const float* __restrict__ bih2, const float* __restrict__ bhh2,
    const float* __restrict__ bproj,
    const float* __restrict__ ws, float* __restrict__ out)
{
  const int tid = threadIdx.x;
  const int r0 = blockIdx.x * RT;

  const float* wt_hh0 = ws + O_HH0;
  const float* wt_ih1 = ws + O_IH1;
  const float* wt_hh1 = ws + O_HH1;
  const float* wt_ih2 = ws + O_IH2;
  const float* wt_hh2 = ws + O_HH2;
  const float* wt_proj = ws + O_PROJ;
  const float* tab = ws + O_TAB;

  float* __restrict__ out_logits = out;
  float* __restrict__ out_pred = out + (size_t)BATCH * SEQ * VOC;

  __shared__ float h0s[RT][H1D];          // 4 KB
  __shared__ float h1s[RT][H2D];          // 2 KB
  __shared__ float h2s[RT][H3D];          // 0.5 KB
  __shared__ float scA[RT][3][H1D];       // 12 KB  (stage A kh=1 partials)
  __shared__ float scBi[RT][3][H2D];      // 6 KB   (stage B gi1 g=1 partials)
  __shared__ float scBh[2][RT][3][H2D];   // 12 KB  (stage B gh1 g=2,3 partials)
  __shared__ float scC[10][3][RT][H3D];   // 15 KB  (stage C partials)
  __shared__ float sc_log[RT][VOC];
  __shared__ int toks[RT];

  // ---- init hidden states: combined = latent @ Winit.T + binit (f64 accumulate)
  for (int idx = tid; idx < RT * 416; idx += NT) {
    int r = idx / 416, jj = idx - r * 416;
    const float* lrow = latent + (size_t)(r0 + r) * LAT;
    const float* wrow = Winit + (size_t)jj * LAT;
    double acc = (double)binit[jj];
    for (int k = 0; k < LAT; ++k) acc += (double)lrow[k] * (double)wrow[k];
    float a = (float)acc;
    if (jj < H1D) h0s[r][jj] = a;
    else if (jj < H1D + H2D) h1s[r][jj - H1D] = a;
    else h2s[r][jj - H1D - H2D] = a;
  }
  __syncthreads();

  for (int t = 0; t < SEQ; ++t) {
    if (tid < RT) toks[tid] = (t == 0) ? SOS : tgt[(size_t)(r0 + tid) * SEQ + t];

    // ======== Stage A: GRU0. j = tid&255, K split in half by kh = tid>>8 ========
    const int j = tid & 255;
    const int kh = tid >> 8;
    {
      double aR[RT], aZ[RT], aN[RT];
      #pragma unroll
      for (int r = 0; r < RT; ++r) { aR[r] = 0.0; aZ[r] = 0.0; aN[r] = 0.0; }
      const float* __restrict__ wbase = wt_hh0 + j;
      const int k0 = kh * 128;
      for (int kb = k0; kb < k0 + 128; kb += 4) {
        float4 hv[RT];
        #pragma unroll
        for (int r = 0; r < RT; ++r) hv[r] = *(const float4*)&h0s[r][kb];
        #pragma unroll
        for (int u = 0; u < 4; ++u) {
          const float* wp = wbase + (size_t)(kb + u) * G1;
          double wr = (double)wp[0], wz = (double)wp[256], wn = (double)wp[512];
          #pragma unroll
          for (int r = 0; r < RT; ++r) {
            double hval = (double)((const float*)&hv[r])[u];
            aR[r] = fma(hval, wr, aR[r]);
            aZ[r] = fma(hval, wz, aZ[r]);
            aN[r] = fma(hval, wn, aN[r]);
          }
        }
      }
      if (kh == 1) {
        #pragma unroll
        for (int r = 0; r < RT; ++r) {
          scA[r][0][j] = (float)aR[r];
          scA[r][1][j] = (float)aZ[r];
          scA[r][2][j] = (float)aN[r];
        }
      }
      __syncthreads();  // B1: partials + toks visible; all h0s reads done
      if (kh == 0) {
        const double bR = (double)bhh0[j], bZ = (double)bhh0[256 + j], bN = (double)bhh0[512 + j];
        float h0n[RT];
        #pragma unroll
        for (int r = 0; r < RT; ++r) {
          const float* trow = tab + (size_t)toks[r] * G1;
          double gR = (double)trow[j] + aR[r] + (double)scA[r][0][j] + bR;
          double gZ = (double)trow[256 + j] + aZ[r] + (double)scA[r][1][j] + bZ;
          double giN = (double)trow[512 + j];
          double ghN = aN[r] + (double)scA[r][2][j] + bN;
          double rg = sigmd(gR);
          double zg = sigmd(gZ);
          double ng = tanh(fma(rg, ghN, giN));
          h0n[r] = (float)((1.0 - zg) * ng + zg * (double)h0s[r][j]);
        }
        #pragma unroll
        for (int r = 0; r < RT; ++r) h0s[r][j] = h0n[r];
      }
    }
    __syncthreads();  // B2: h0s new visible

    // ======== Stage B: GRU1. jb = tid&127; g = tid>>7: g0,g1 = gi1 K-halves (new h0s),
    //                                                     g2,g3 = gh1 K-halves (old h1s) ========
    const int jb = tid & 127;
    const int g = tid >> 7;
    {
      double bRv[RT], bZv[RT], bNv[RT];
      #pragma unroll
      for (int r = 0; r < RT; ++r) { bRv[r] = 0.0; bZv[r] = 0.0; bNv[r] = 0.0; }
      if (g < 2) {
        const float* __restrict__ wbase = wt_ih1 + jb;
        const int k0 = g * 128;
        for (int kb = k0; kb < k0 + 128; kb += 4) {
          float4 hv[RT];
          #pragma unroll
          for (int r = 0; r < RT; ++r) hv[r] = *(const float4*)&h0s[r][kb];
          #pragma unroll
          for (int u = 0; u < 4; ++u) {
            const float* wp = wbase + (size_t)(kb + u) * G2;
            double wr = (double)wp[0], wz = (double)wp[128], wn = (double)wp[256];
            #pragma unroll
            for (int r = 0; r < RT; ++r) {
              double hval = (double)((const float*)&hv[r])[u];
              bRv[r] = fma(hval, wr, bRv[r]);
              bZv[r] = fma(hval, wz, bZv[r]);
              bNv[r] = fma(hval, wn, bNv[r]);
            }
          }
        }
        if (g == 1) {
          #pragma unroll
          for (int r = 0; r < RT; ++r) {
            scBi[r][0][jb] = (float)bRv[r];
            scBi[r][1][jb] = (float)bZv[r];
            scBi[r][2][jb] = (float)bNv[r];
          }
        }
      } else {
        const float* __restrict__ wbase = wt_hh1 + jb;
        const int k0 = (g - 2) * 64;
        for (int kb = k0; kb < k0 + 64; kb += 4) {
          float4 hv[RT];
          #pragma unroll
          for (int r = 0; r < RT; ++r) hv[r] = *(const float4*)&h1s[r][kb];
          #pragma unroll
          for (int u = 0; u < 4; ++u) {
            const float* wp = wbase + (size_t)(kb + u) * G2;
            double wr = (double)wp[0], wz = (double)wp[128], wn = (double)wp[256];
            #pragma unroll
            for (int r = 0; r < RT; ++r) {
              double hval = (double)((const float*)&hv[r])[u];
              bRv[r] = fma(hval, wr, bRv[r]);
              bZv[r] = fma(hval, wz, bZv[r]);
              bNv[r] = fma(hval, wn, bNv[r]);
            }
          }
        }
        #pragma unroll
        for (int r = 0; r < RT; ++r) {
          scBh[g - 2][r][0][jb] = (float)bRv[r];
          scBh[g - 2][r][1][jb] = (float)bZv[r];
          scBh[g - 2][r][2][jb] = (float)bNv[r];
        }
      }
      __syncthreads();  // B3: partials visible; all h1s reads done
      if (g == 0) {
        const double biR = (double)bih1[jb], biZ = (double)bih1[128 + jb], biN = (double)bih1[256 + jb];
        const double bhR = (double)bhh1[jb], bhZ = (double)bhh1[128 + jb], bhN = (double)bhh1[256 + jb];
        float h1n[RT];
        #pragma unroll
        for (int r = 0; r < RT; ++r) {
          double giR = bRv[r] + (double)scBi[r][0][jb] + biR;
          double giZ = bZv[r] + (double)scBi[r][1][jb] + biZ;
          double giN = bNv[r] + (double)scBi[r][2][jb] + biN;
          double ghR = (double)scBh[0][r][0][jb] + (double)scBh[1][r][0][jb] + bhR;
          double ghZ = (double)scBh[0][r][1][jb] + (double)scBh[1][r][1][jb] + bhZ;
          double ghN = (double)scBh[0][r][2][jb] + (double)scBh[1][r][2][jb] + bhN;
          double rg = sigmd(giR + ghR);
          double zg = sigmd(giZ + ghZ);
          double ng = tanh(fma(rg, ghN, giN));
          h1n[r] = (float)((1.0 - zg) * ng + zg * (double)h1s[r][jb]);
        }
        #pragma unroll
        for (int r = 0; r < RT; ++r) h1s[r][jb] = h1n[r];
      }
    }
    __syncthreads();  // B4: h1s new visible

    // ======== Stage C: GRU2. jc = tid&31; sc = tid>>5: sc0..7 = gi2 K-slices of 16 (new h1s),
    //                                                    sc8,9 = gh2 K-slices of 16 (old h2s) ========
    const int jc = tid & 31;
    const int sc = tid >> 5;  // 0..15
    {
      double cR[RT], cZ[RT], cN[RT];
      #pragma unroll
      for (int r = 0; r < RT; ++r) { cR[r] = 0.0; cZ[r] = 0.0; cN[r] = 0.0; }
      if (sc < 8) {
        for (int kk = 0; kk < 16; ++kk) {
          int k = sc * 16 + kk;
          const float* wp = wt_ih2 + (size_t)k * G3;
          double wr = (double)wp[jc], wz = (double)wp[32 + jc], wn = (double)wp[64 + jc];
          #pragma unroll
          for (int r = 0; r < RT; ++r) {
            double hval = (double)h1s[r][k];
            cR[r] = fma(hval, wr, cR[r]);
            cZ[r] = fma(hval, wz, cZ[r]);
            cN[r] = fma(hval, wn, cN[r]);
          }
        }
      } else if (sc < 10) {
        for (int kk = 0; kk < 16; ++kk) {
          int k = (sc - 8) * 16 + kk;
          const float* wp = wt_hh2 + (size_t)k * G3;
          double wr = (double)wp[jc], wz = (double)wp[32 + jc], wn = (double)wp[64 + jc];
          #pragma unroll
          for (int r = 0; r < RT; ++r) {
            double hval = (double)h2s[r][k];
            cR[r] = fma(hval, wr, cR[r]);
            cZ[r] = fma(hval, wz, cZ[r]);
            cN[r] = fma(hval, wn, cN[r]);
          }
        }
      }
      if (sc < 10) {
        #pragma unroll
        for (int r = 0; r < RT; ++r) {
          scC[sc][0][r][jc] = (float)cR[r];
          scC[sc][1][r][jc] = (float)cZ[r];
          scC[sc][2][r][jc] = (float)cN[r];
        }
      }
    }
    __syncthreads();  // B5: partials visible; all h2s reads done
    if (tid < 128) {
      int r = tid >> 5, jj = tid & 31;
      double giR = (double)bih2[jj], giZ = (double)bih2[32 + jj], giN = (double)bih2[64 + jj];
      #pragma unroll
      for (int s = 0; s < 8; ++s) {
        giR += (double)scC[s][0][r][jj];
        giZ += (double)scC[s][1][r][jj];
        giN += (double)scC[s][2][r][jj];
      }
      double ghR = (double)scC[8][0][r][jj] + (double)scC[9][0][r][jj] + (double)bhh2[jj];
      double ghZ = (double)scC[8][1][r][jj] + (double)scC[9][1][r][jj] + (double)bhh2[32 + jj];
      double ghN = (double)scC[8][2][r][jj] + (double)scC[9][2][r][jj] + (double)bhh2[64 + jj];
      double rg = sigmd(giR + ghR);
      double zg = sigmd(giZ + ghZ);
      double ng = tanh(fma(rg, ghN, giN));
      h2s[r][jj] = (float)((1.0 - zg) * ng + zg * (double)h2s[r][jj]);
    }
    __syncthreads();  // B6: h2s new visible

    // ======== Stage D: projection + argmax ========
    if (tid < RT * VOC) {
      int r = tid / VOC, c = tid - r * VOC;
      double acc = (double)bproj[c];
      #pragma unroll
      for (int k = 0; k < H3D; ++k)
        acc = fma((double)h2s[r][k], (double)wt_proj[k * VOC + c], acc);
      float accf = (float)acc;
      out_logits[((size_t)(r0 + r) * SEQ + t) * VOC + c] = accf;
      sc_log[r][c] = accf;
    }
    __syncthreads();  // B7: logits visible
    if (tid < RT) {
      float best = sc_log[tid][0];
      int bi = 0;
      #pragma unroll
      for (int c = 1; c < VOC; ++c) {
        float v = sc_log[tid][c];
        if (v > best) { best = v; bi = c; }
      }
      out_pred[(size_t)(r0 + tid) * SEQ + t] = (float)bi;
    }
    // Hazard audit: every shared buffer's writer at t+1 is separated from its
    // reader at t by >=1 of B2..B7 (see per-buffer notes in session journal).
  }
}

extern "C" void kernel_launch(void* const* d_in, const int* in_sizes, int n_in,
                              void* d_out, int out_size, void* d_ws, size_t ws_size,
                              hipStream_t stream) {
  const float* latent  = (const float*)d_in[0];
  const int*   tgt     = (const int*)d_in[1];
  const float* Wemb    = (const float*)d_in[2];
  const float* bemb    = (const float*)d_in[3];
  const float* Winit   = (const float*)d_in[4];
  const float* binit   = (const float*)d_in[5];
  const float* Wih0    = (const float*)d_in[6];
  const float* Whh0    = (const float*)d_in[7];
  const float* bih0    = (const float*)d_in[8];
  const float* bhh0    = (const float*)d_in[9];
  const float* Wih1    = (const float*)d_in[10];
  const float* Whh1    = (const float*)d_in[11];
  const float* bih1    = (const float*)d_in[12];
  const float* bhh1    = (const float*)d_in[13];
  const float* Wih2    = (const float*)d_in[14];
  const float* Whh2    = (const float*)d_in[15];
  const float* bih2    = (const float*)d_in[16];
  const float* bhh2    = (const float*)d_in[17];
  const float* Wproj   = (const float*)d_in[18];
  const float* bproj   = (const float*)d_in[19];

  float* ws = (float*)d_ws;
  float* out = (float*)d_out;

  int setup_threads = WS_FLOATS;
  int setup_blocks = (setup_threads + 255) / 256;
  setup_kernel<<<setup_blocks, 256, 0, stream>>>(Whh0, Wih1, Whh1, Wih2, Whh2, Wproj,
                                                Wemb, bemb, Wih0, bih0, ws);

  gru_persist<<<BATCH / RT, NT, 0, stream>>>(latent, tgt, Winit, binit,
                                             bhh0, bih1, bhh1, bih2, bhh2, bproj,
                                             ws, out);
}